// Round 7
// baseline (122.084 us; speedup 1.0000x reference)
//
#include <hip/hip_runtime.h>
#include <math.h>

#define NN 8
#define CC 20
#define PP 8732
#define MM 16
#define NPR 3
#define ROWS (NN * CC)

// Kernel A geometry: 8 chunks/row, 256 threads, <=5 priors/thread
#define SPL 8
#define CH2 1092            // ceil(PP/SPL); 8*1092 = 8736 >= 8732
#define TBA 256
#define KA 5                // ceil(CH2/TBA)

// Kernel B geometry
#define FBLK 1024
#define EPT 9               // ceil(PP/FBLK)

__device__ __forceinline__ float fast_rcp(float x) { return __builtin_amdgcn_rcpf(x); }
__device__ __forceinline__ float rfl(float x) {   // force wave-uniform value into SGPR
    return __uint_as_float(__builtin_amdgcn_readfirstlane(__float_as_uint(x)));
}

// fast lse over 2 logits: mx + log(1 + exp(-|a-b|)); single definition used
// everywhere so recomputed terms cancel bit-exactly.
__device__ __forceinline__ float lse2(float a, float b) {
    float mx = fmaxf(a, b);
    float d  = fabsf(a - b);
    return mx + __logf(1.0f + __expf(-d));
}

// ---------------- Kernel A: matching + ce on full chip ----------------
// Round-6 lesson: fused 160-block kernel left 37% of CUs idle and was
// latency-bound (VALUBusy 31%, occ 24%). Matching parallelizes over priors:
// 1280 blocks x 256 thr, ~5 KB LDS, 4 passes x 4 boxes (20 uniform values
// fit SGPRs; ~35 VGPR -> no scratch at any budget; proven in round 6).
// Writes ce VALUES to global (round-1's sin was recomputing lse in B).
__global__ __launch_bounds__(TBA) void mbox_match(
    const float* __restrict__ locs, const float* __restrict__ scores,
    const float* __restrict__ boxes, const int* __restrict__ labels,
    const float* __restrict__ priors,
    float* __restrict__ cef, unsigned char* __restrict__ pk8,
    unsigned long long* __restrict__ partials, float* __restrict__ cstats)
{
    const int row = blockIdx.x / SPL;
    const int chunk = blockIdx.x - row * SPL;
    const int tid = threadIdx.x, lane = tid & 63, wav = tid >> 6;
    const int p0 = chunk * CH2, p1e = min(p0 + CH2, PP);

    __shared__ unsigned int s_u32[CH2];             // per-prior packed bovk key
    __shared__ unsigned long long s_pk64[4 * MM];   // per-wave per-object argmax keys
    __shared__ float s_bcx[MM], s_bcy[MM], s_bw[MM], s_bh[MM];
    __shared__ float s_rf[4 * 3];

    const float* bb = boxes + (size_t)row * MM * 4;
    unsigned int labm = 0;
    {
        const int* lb = labels + (size_t)row * MM;
#pragma unroll
        for (int m = 0; m < MM; m++) labm |= (lb[m] != 0 ? 1u : 0u) << m;
        labm = __builtin_amdgcn_readfirstlane(labm);
    }
    if (tid < MM) {
        const float* b = bb + tid * 4;
        float x1 = b[0], y1 = b[1], x2 = b[2], y2 = b[3];
        s_bcx[tid] = (x1 + x2) * 0.5f;
        s_bcy[tid] = (y1 + y2) * 0.5f;
        s_bw[tid]  = x2 - x1;
        s_bh[tid]  = y2 - y1;
    }
    __syncthreads();

    const float4* pri4 = (const float4*)priors;
    const float4* loc4 = (const float4*)(locs + (size_t)row * PP * 4);
    const float2* sc2  = (const float2*)(scores + (size_t)row * PP * 2);

    // ---- matching: four passes of 4 boxes (20 uniform values fit SGPRs) ----
#pragma unroll
    for (int pass4 = 0; pass4 < 4; pass4++) {
        const int m0 = pass4 * 4;
        float x1[4], y1[4], x2[4], y2[4], ar[4];
#pragma unroll
        for (int m = 0; m < 4; m++) {
            float a1 = rfl(bb[(m0 + m) * 4 + 0]), b1 = rfl(bb[(m0 + m) * 4 + 1]);
            float a2 = rfl(bb[(m0 + m) * 4 + 2]), b2 = rfl(bb[(m0 + m) * 4 + 3]);
            x1[m] = a1; y1[m] = b1; x2[m] = a2; y2[m] = b2;
            ar[m] = rfl((a2 - a1) * (b2 - b1));
        }
        // bestk4[m]: (iou_bits & ~0xF) | (8-k); u32-max == (max trunc4-iou, min k == min p)
        unsigned int bestk4[4];
#pragma unroll
        for (int m = 0; m < 4; m++) bestk4[m] = 0u;

#pragma unroll
        for (int k = 0; k < KA; k++) {
            const int p = p0 + tid + k * TBA;
            if (p >= p1e) continue;
            float4 pr = pri4[p];
            const unsigned int lowb = (unsigned int)(8 - k);
            float hw = pr.z * 0.5f, hh = pr.w * 0.5f;
            float px1 = pr.x - hw, py1 = pr.y - hh;
            float px2 = pr.x + hw, py2 = pr.y + hh;
            float area_b = (px2 - px1) * (py2 - py1);
            unsigned int bv = (pass4 == 0) ? 0u : s_u32[tid + k * TBA];  // thread-private slot
#pragma unroll
            for (int m = 0; m < 4; m++) {
                float dx = fminf(x2[m], px2) - fmaxf(x1[m], px1);
                float dy = fminf(y2[m], py2) - fmaxf(y1[m], py1);
                dx = fmaxf(dx, 0.0f); dy = fmaxf(dy, 0.0f);
                float inter = dx * dy;
                float den = (ar[m] + area_b) - inter;
                float iou = inter * fast_rcp(den);
                unsigned int ib = __float_as_uint(iou);
                bv        = max(bv,        (ib & 0xFFFFFFF0u) | (unsigned int)(15 - (m0 + m)));
                bestk4[m] = max(bestk4[m], (ib & 0xFFFFFFF0u) | lowb);
            }
            s_u32[tid + k * TBA] = bv;
        }

        // per-object argmax: expand winner to exact-p u64 key, wave reduce
#pragma unroll
        for (int m = 0; m < 4; m++) {
            unsigned int bk = bestk4[m];
            int kk = 8 - (int)(bk & 0xFu);
            int pb = p0 + tid + kk * TBA;
            unsigned long long key = ((unsigned long long)(bk & 0xFFFFFFF0u) << 32)
                                   | (unsigned int)(0x7fffffff - pb);
#pragma unroll
            for (int off = 32; off; off >>= 1) {
                unsigned long long o = __shfl_down(key, off);
                if (o > key) key = o;
            }
            if (lane == 0) s_pk64[wav * MM + m0 + m] = key;
        }
        // keep each pass's box SGPR set from being co-hoisted with the next
        __builtin_amdgcn_sched_barrier(0);
    }

    // ---- pos/ce pass: scores read exactly once; write ce + pk to global ----
    float l_np = 0.0f, l_l1 = 0.0f, l_cp = 0.0f;
#pragma unroll
    for (int k = 0; k < KA; k++) {
        const int p = p0 + tid + k * TBA;
        if (p >= p1e) continue;
        unsigned int bv = s_u32[tid + k * TBA];
        int bm = 15 - (int)(bv & 15u);
        bool pos = (bv >= 0x3F000000u) && (((labm >> bm) & 1u) != 0u);
        pk8[(size_t)row * PP + p] = (unsigned char)((pos ? 16u : 0u) | (unsigned)bm);
        float2 sc = sc2[p];
        float lse = lse2(sc.x, sc.y);
        float ce;
        if (pos) {      // rare, divergent cold path
            float4 pr = pri4[p];
            float4 pl = loc4[p];
            l_np += 1.0f;
            l_cp += lse - sc.y;
            float tx = (s_bcx[bm] - pr.x) * 10.0f / pr.z;
            float ty = (s_bcy[bm] - pr.y) * 10.0f / pr.w;
            float tw = __logf(s_bw[bm] / pr.z) * 5.0f;
            float th = __logf(s_bh[bm] / pr.w) * 5.0f;
            l_l1 += fabsf(pl.x - tx) + fabsf(pl.y - ty) + fabsf(pl.z - tw) + fabsf(pl.w - th);
            ce = 0.0f;
        } else {
            ce = fmaxf(lse - sc.x, 0.0f);
        }
        cef[(size_t)row * PP + p] = ce;
    }

#pragma unroll
    for (int off = 32; off; off >>= 1) {
        l_np += __shfl_down(l_np, off);
        l_l1 += __shfl_down(l_l1, off);
        l_cp += __shfl_down(l_cp, off);
    }
    if (lane == 0) { s_rf[wav * 3] = l_np; s_rf[wav * 3 + 1] = l_l1; s_rf[wav * 3 + 2] = l_cp; }
    __syncthreads();

    if (tid < MM) {
        unsigned long long key = s_pk64[tid];
        for (int w = 1; w < 4; w++) {
            unsigned long long o = s_pk64[w * MM + tid];
            if (o > key) key = o;
        }
        partials[((size_t)row * MM + tid) * SPL + chunk] = key;
    }
    if (tid == 0) {
        float np = 0, l1 = 0, cp = 0;
        for (int w = 0; w < 4; w++) { np += s_rf[w * 3]; l1 += s_rf[w * 3 + 1]; cp += s_rf[w * 3 + 2]; }
        float* cs = cstats + ((size_t)row * SPL + chunk) * 3;
        cs[0] = np; cs[1] = l1; cs[2] = cp;
    }
}

// ---------------- Kernel B: force prologue + radix-select top-K ----------------
__global__ __launch_bounds__(FBLK) void mbox_sel(
    const float* __restrict__ locs, const float* __restrict__ scores,
    const float* __restrict__ boxes, const int* __restrict__ labels,
    const float* __restrict__ priors,
    const float* __restrict__ cef, const unsigned char* __restrict__ pk8,
    const unsigned long long* __restrict__ partials,
    const float* __restrict__ cstats, float* __restrict__ rstats)
{
    const int row = blockIdx.x, tid = threadIdx.x, lane = tid & 63, wav = tid >> 6;

    __shared__ unsigned int s_u32[PP];              // ce bit patterns
    __shared__ float s_bcx[MM], s_bcy[MM], s_bw[MM], s_bh[MM];
    __shared__ int s_lab[MM], s_pfo[MM];
    __shared__ float s_sum[3];
    __shared__ unsigned int s_hist[256];
    __shared__ unsigned int s_prefix, s_Kr, s_K;
    __shared__ float s_redf[16];
    __shared__ int s_redi[16];

    if (tid < MM) {
        const float* b = boxes + ((size_t)row * MM + tid) * 4;
        float x1 = b[0], y1 = b[1], x2 = b[2], y2 = b[3];
        s_bcx[tid] = (x1 + x2) * 0.5f; s_bcy[tid] = (y1 + y2) * 0.5f;
        s_bw[tid] = x2 - x1; s_bh[tid] = y2 - y1;
        s_lab[tid] = labels[row * MM + tid];
        const unsigned long long* pr = partials + ((size_t)row * MM + tid) * SPL;
        unsigned long long key = pr[0];
        for (int c = 1; c < SPL; c++) { unsigned long long o = pr[c]; if (o > key) key = o; }
        s_pfo[tid] = 0x7fffffff - (int)(unsigned)(key & 0xffffffffull);
    }
    if (tid >= 16 && tid < 19) {
        int j = tid - 16; float s = 0;
        for (int c = 0; c < SPL; c++) s += cstats[((size_t)row * SPL + c) * 3 + j];
        s_sum[j] = s;
    }
    // load ce bit patterns into LDS (coalesced)
#pragma unroll
    for (int k = 0; k < EPT; k++) {
        const int p = tid + k * FBLK;
        if (p < PP) s_u32[p] = __float_as_uint(cef[(size_t)row * PP + p]);
    }
    __syncthreads();

    // force deltas (sequential last-wins == group by prior, keep largest m);
    // patches s_u32[p] in place, covered by the next __syncthreads.
    const float4* loc4 = (const float4*)(locs + (size_t)row * PP * 4);
    const float2* sc2  = (const float2*)(scores + (size_t)row * PP * 2);
    float d_np = 0, d_l1 = 0, d_cp = 0;
    if (tid < MM) {
        int p = s_pfo[tid];
        bool is_last = true;
        for (int mm = tid + 1; mm < MM; mm++) if (s_pfo[mm] == p) is_last = false;
        if (is_last) {
            const float4 pr = ((const float4*)priors)[p];
            const float4 pl = loc4[p];
            const float2 sc = sc2[p];
            float lse = lse2(sc.x, sc.y);
            unsigned int u = pk8[(size_t)row * PP + p];
            if (u & 16u) {   // remove old positive contribution
                int mo = u & 15;
                d_np -= 1.0f; d_cp -= (lse - sc.y);
                float tx = (s_bcx[mo] - pr.x) * 10.0f / pr.z;
                float ty = (s_bcy[mo] - pr.y) * 10.0f / pr.w;
                float tw = __logf(s_bw[mo] / pr.z) * 5.0f;
                float th = __logf(s_bh[mo] / pr.w) * 5.0f;
                d_l1 -= fabsf(pl.x - tx) + fabsf(pl.y - ty) + fabsf(pl.z - tw) + fabsf(pl.w - th);
            }
            if (s_lab[tid] != 0) {   // add forced positive (ov=1, m=tid)
                d_np += 1.0f; d_cp += (lse - sc.y);
                float tx = (s_bcx[tid] - pr.x) * 10.0f / pr.z;
                float ty = (s_bcy[tid] - pr.y) * 10.0f / pr.w;
                float tw = __logf(s_bw[tid] / pr.z) * 5.0f;
                float th = __logf(s_bh[tid] / pr.w) * 5.0f;
                d_l1 += fabsf(pl.x - tx) + fabsf(pl.y - ty) + fabsf(pl.z - tw) + fabsf(pl.w - th);
                s_u32[p] = 0u;                             // forced positive -> ce 0
            } else {
                s_u32[p] = __float_as_uint(fmaxf(lse - sc.x, 0.0f)); // forced, label 0
            }
        }
    }
    if (tid < 64) {
#pragma unroll
        for (int off = 32; off; off >>= 1) {
            d_np += __shfl_down(d_np, off);
            d_l1 += __shfl_down(d_l1, off);
            d_cp += __shfl_down(d_cp, off);
        }
        if (tid == 0) {
            float np = s_sum[0] + d_np;
            rstats[(size_t)row * 8 + 0] = np;
            rstats[(size_t)row * 8 + 1] = s_sum[1] + d_l1;
            rstats[(size_t)row * 8 + 2] = s_sum[2] + d_cp;
            int K = NPR * (int)(np + 0.5f);
            s_K = (K > 0) ? (unsigned)K : 0u;
            s_prefix = 0u;
            s_Kr = (K > 0) ? (unsigned)K : 0u;
        }
    }
    __syncthreads();

    // 4-pass 256-bin histogram radix select for the K-th largest bit pattern
    const unsigned int K = s_K;
    unsigned int T = 0u;
    if (K > 0u && K < PP) {
        for (int pass = 0; pass < 4; pass++) {
            const int shift = 24 - 8 * pass;
            if (tid < 256) s_hist[tid] = 0u;
            __syncthreads();
            const unsigned int pref   = s_prefix;
            const unsigned int maskhi = (pass == 0) ? 0u : (0xffffffffu << (shift + 8));
#pragma unroll
            for (int k = 0; k < EPT; k++) {
                const int p = tid + k * FBLK;
                unsigned int u = (p < PP) ? s_u32[p] : 0u;
                if ((u & maskhi) == pref) atomicAdd(&s_hist[(u >> shift) & 255u], 1u);
            }
            __syncthreads();
            if (wav == 0) {
                unsigned int Kr = s_Kr;
                unsigned int h0 = s_hist[lane * 4 + 0];
                unsigned int h1 = s_hist[lane * 4 + 1];
                unsigned int h2 = s_hist[lane * 4 + 2];
                unsigned int h3 = s_hist[lane * 4 + 3];
                unsigned int c3 = h3;
                unsigned int c2 = h3 + h2;
                unsigned int c1 = c2 + h1;
                unsigned int c0 = c1 + h0;
                unsigned int suf = c0;
#pragma unroll
                for (int off = 1; off < 64; off <<= 1) {
                    unsigned int o = __shfl_down(suf, off);
                    if (lane + off < 64) suf += o;
                }
                unsigned int above = suf - c0;
                int cand = -1;
                unsigned int G = 0;
                if      (c3 + above >= Kr) { cand = lane * 4 + 3; G = above + c3 - h3; }
                else if (c2 + above >= Kr) { cand = lane * 4 + 2; G = above + c2 - h2; }
                else if (c1 + above >= Kr) { cand = lane * 4 + 1; G = above + c1 - h1; }
                else if (c0 + above >= Kr) { cand = lane * 4 + 0; G = above + c0 - h0; }
                int best = cand;
#pragma unroll
                for (int off = 32; off; off >>= 1) best = max(best, __shfl_down(best, off));
                best = __shfl(best, 0);
                if (cand == best && cand >= 0) {
                    s_Kr = Kr - G;
                    s_prefix = pref | ((unsigned int)best << shift);
                }
            }
            __syncthreads();
        }
        T = s_prefix;
    }

    // sum strictly greater than pivot + ties * pivot
    float sgt = 0.0f; int cgt = 0;
    if (K > 0u) {
#pragma unroll
        for (int k = 0; k < EPT; k++) {
            const int p = tid + k * FBLK;
            unsigned int u = (p < PP) ? s_u32[p] : 0u;
            if (u > T) { sgt += __uint_as_float(u); cgt++; }
        }
    }
#pragma unroll
    for (int off = 32; off; off >>= 1) {
        sgt += __shfl_down(sgt, off);
        cgt += __shfl_down(cgt, off);
    }
    if (lane == 0) { s_redf[wav] = sgt; s_redi[wav] = cgt; }
    __syncthreads();
    if (tid == 0) {
        float s = 0; int cnt = 0;
        for (int w = 0; w < 16; w++) { s += s_redf[w]; cnt += s_redi[w]; }
        float chard = (K > 0u) ? (s + (float)(int)(K - (unsigned)cnt) * __uint_as_float(T)) : 0.0f;
        rstats[(size_t)row * 8 + 4] = chard;
    }
}

// ---------------- Final cross-row reduction ----------------
__global__ void mbox_finalize(const float* __restrict__ rstats, float* __restrict__ out) {
    int c = threadIdx.x;
    float loss = 0.0f;
    if (c < CC) {
        float np = 0, l1 = 0, cp = 0, ch = 0;
        for (int n = 0; n < NN; n++) {
            const float* s = rstats + ((size_t)(n * CC + c)) * 8;
            np += s[0]; l1 += s[1]; cp += s[2]; ch += s[4];
        }
        float loc = l1 / fmaxf(np * 4.0f, 1.0f);
        float val = (np > 0.0f) ? (cp + ch + loc) / fmaxf(np, 1.0f) : 0.0f;
        loss = val / (float)CC;
    }
#pragma unroll
    for (int off = 32; off; off >>= 1) loss += __shfl_down(loss, off);
    if (threadIdx.x == 0) out[0] = loss;
}

extern "C" void kernel_launch(void* const* d_in, const int* in_sizes, int n_in,
                              void* d_out, int out_size, void* d_ws, size_t ws_size,
                              hipStream_t stream) {
    const float* locs   = (const float*)d_in[0];
    const float* scores = (const float*)d_in[1];
    const float* boxes  = (const float*)d_in[2];
    const int*   labels = (const int*)d_in[3];
    const float* priors = (const float*)d_in[4];
    float* out = (float*)d_out;

    char* ws = (char*)d_ws;
    float* cef                   = (float*)ws;                          // 5,588,480 B
    unsigned char* pk8           = (unsigned char*)(ws + 5588480);      // 1,397,120 B
    unsigned long long* partials = (unsigned long long*)(ws + 6985600); //   163,840 B
    float* cstats                = (float*)(ws + 7149440);              //    15,360 B
    float* rstats                = (float*)(ws + 7164800);              //     5,120 B

    mbox_match<<<ROWS * SPL, TBA, 0, stream>>>(locs, scores, boxes, labels, priors,
                                               cef, pk8, partials, cstats);
    mbox_sel<<<ROWS, FBLK, 0, stream>>>(locs, scores, boxes, labels, priors,
                                        cef, pk8, partials, cstats, rstats);
    mbox_finalize<<<1, 64, 0, stream>>>(rstats, out);
}

// Round 8
// 121.608 us; speedup vs baseline: 1.0039x; 1.0039x over previous
//
#include <hip/hip_runtime.h>
#include <math.h>

#define NN 8
#define CC 20
#define PP 8732
#define MM 16
#define NPR 3
#define ROWS (NN * CC)

// Kernel A geometry (round-1 proven): 12 chunks/row, 256 thr, 3 priors/thread
#define SPLIT 12
#define CH 728              // ceil(PP/SPLIT)
#define ABLK 256

// Kernel B geometry
#define FBLK 1024
#define EPT 9               // ceil(PP/FBLK)

__device__ __forceinline__ float fast_rcp(float x) { return __builtin_amdgcn_rcpf(x); }
__device__ __forceinline__ float rfl(float x) {   // force wave-uniform value into SGPR
    return __uint_as_float(__builtin_amdgcn_readfirstlane(__float_as_uint(x)));
}

// fast lse over 2 logits: mx + log(1 + exp(-|a-b|)); single definition used
// everywhere so recomputed terms cancel bit-exactly.
__device__ __forceinline__ float lse2(float a, float b) {
    float mx = fmaxf(a, b);
    float d  = fabsf(a - b);
    return mx + __logf(1.0f + __expf(-d));
}

// ---------------- Kernel A: IoU matching + ce (round-1 p1 + fused ce write) ----------------
// Round-7 lesson: the 4-pass/4-box split re-read boxes+priors per pass behind
// sched_barriers -> latency-serialized (45 µs). Round-1's single-pass 16-box
// SGPR-resident loop with prior prefetch was <42 µs at 256-thr blocks (no
// spill: per-thread state is bestk[16]+temps; the round-3/4 spills came from
// the fused kernel's 1024-thr budget, not this structure). Addition vs round
// 1: scores prefetched in the hot loop, ce written to cef[] so kernel B never
// re-reads scores / recomputes lse2 in bulk.
__global__ __launch_bounds__(ABLK) void mbox_p1(
    const float* __restrict__ locs, const float* __restrict__ scores,
    const float* __restrict__ boxes, const int* __restrict__ labels,
    const float* __restrict__ priors,
    float* __restrict__ cef, unsigned char* __restrict__ pk8,
    unsigned long long* __restrict__ partials, float* __restrict__ cstats)
{
    const int row = blockIdx.x / SPLIT;
    const int chunk = blockIdx.x - row * SPLIT;
    const int tid = threadIdx.x, lane = tid & 63, wav = tid >> 6;

    // cold-path data (divergent bm index) lives in LDS; hot loop never touches LDS
    __shared__ float s_bcx[MM], s_bcy[MM], s_bw[MM], s_bh[MM];
    __shared__ unsigned int s_pk[4 * MM];
    __shared__ float s_rf[4 * 3];

    // wave-uniform box data -> readfirstlane -> SGPR residency
    float bx1[MM], by1[MM], bx2[MM], by2[MM], bar[MM];
    unsigned int labm = 0;
    {
        const float* bb = boxes + (size_t)row * MM * 4;
        const int*   lb = labels + (size_t)row * MM;
#pragma unroll
        for (int m = 0; m < MM; m++) {
            float x1 = rfl(bb[m * 4 + 0]), y1 = rfl(bb[m * 4 + 1]);
            float x2 = rfl(bb[m * 4 + 2]), y2 = rfl(bb[m * 4 + 3]);
            bx1[m] = x1; by1[m] = y1; bx2[m] = x2; by2[m] = y2;
            bar[m] = rfl((x2 - x1) * (y2 - y1));
            labm |= (lb[m] != 0 ? 1u : 0u) << m;
        }
        labm = __builtin_amdgcn_readfirstlane(labm);
    }
    if (tid < MM) {
        s_bcx[tid] = (bx1[tid] + bx2[tid]) * 0.5f;
        s_bcy[tid] = (by1[tid] + by2[tid]) * 0.5f;
        s_bw[tid]  = bx2[tid] - bx1[tid];
        s_bh[tid]  = by2[tid] - by1[tid];
    }
    __syncthreads();

    const float4* pri4 = (const float4*)priors;
    const float4* loc4 = (const float4*)(locs + (size_t)row * PP * 4);
    const float2* sc2  = (const float2*)(scores + (size_t)row * PP * 2);
    unsigned char* pk  = pk8 + (size_t)row * PP;
    float* cefr        = cef + (size_t)row * PP;

    // bestk[m]: (iou_bits & ~0x7FF) | ((7-it)<<8) | (255-tid)
    //   u32-max == (max trunc-iou, then min it, then min tid) == (max iou, min p)
    unsigned int bestk[MM];
#pragma unroll
    for (int m = 0; m < MM; m++) bestk[m] = 0u;
    float l_np = 0.0f, l_l1 = 0.0f, l_cp = 0.0f;
    const int p0 = chunk * CH, p1e = min(p0 + CH, PP);

    float4 pr_next; float2 sc_next;
    if (p0 + tid < p1e) { pr_next = pri4[p0 + tid]; sc_next = sc2[p0 + tid]; }
    int it = 0;
    for (int p = p0 + tid; p < p1e; p += ABLK, ++it) {
        float4 pr = pr_next;
        float2 sc = sc_next;
        if (p + ABLK < p1e) { pr_next = pri4[p + ABLK]; sc_next = sc2[p + ABLK]; }
        const unsigned int lowb = ((unsigned int)(7 - it) << 8) | (unsigned int)(255 - tid);
        float hw = pr.z * 0.5f, hh = pr.w * 0.5f;
        float px1 = pr.x - hw, py1 = pr.y - hh;
        float px2 = pr.x + hw, py2 = pr.y + hh;
        float area_b = (px2 - px1) * (py2 - py1);
        // bovk: (iou_bits & ~15) | (15-m); u32-max == (max trunc-iou, min m)
        unsigned int bovk = 0u;
#pragma unroll
        for (int m = 0; m < MM; m++) {
            float dx = fminf(bx2[m], px2) - fmaxf(bx1[m], px1);
            float dy = fminf(by2[m], py2) - fmaxf(by1[m], py1);
            dx = fmaxf(dx, 0.0f); dy = fmaxf(dy, 0.0f);
            float inter = dx * dy;
            float den = (bar[m] + area_b) - inter;
            float iou = inter * fast_rcp(den);
            unsigned int ib = __float_as_uint(iou);
            unsigned int km = (ib & 0xFFFFFFF0u) | (unsigned int)(15 - m);   // v_and_or
            bovk = max(bovk, km);                                            // v_max_u32
            unsigned int kp = (ib & 0xFFFFF800u) | lowb;                     // v_and_or
            bestk[m] = max(bestk[m], kp);                                    // v_max_u32
        }
        int bm = 15 - (int)(bovk & 15u);
        bool pos = (bovk >= 0x3F000000u) && (((labm >> bm) & 1u) != 0u);
        pk[p] = (unsigned char)((pos ? 16u : 0u) | (unsigned)bm);
        float lse = lse2(sc.x, sc.y);
        float ce;
        if (pos) {   // rare, divergent cold path
            float4 pl = loc4[p];
            l_np += 1.0f;
            l_cp += lse - sc.y;
            float tx = (s_bcx[bm] - pr.x) * 10.0f / pr.z;
            float ty = (s_bcy[bm] - pr.y) * 10.0f / pr.w;
            float tw = __logf(s_bw[bm] / pr.z) * 5.0f;
            float th = __logf(s_bh[bm] / pr.w) * 5.0f;
            l_l1 += fabsf(pl.x - tx) + fabsf(pl.y - ty) + fabsf(pl.z - tw) + fabsf(pl.w - th);
            ce = 0.0f;
        } else {
            ce = fmaxf(lse - sc.x, 0.0f);
        }
        cefr[p] = ce;
    }

    // per-object argmax reduce: u32 keys (ties impossible — tid bits differ)
#pragma unroll
    for (int m = 0; m < MM; m++) {
        unsigned int key = bestk[m];
#pragma unroll
        for (int off = 32; off; off >>= 1) {
            unsigned int o = __shfl_down(key, off);
            if (o > key) key = o;
        }
        if (lane == 0) s_pk[wav * MM + m] = key;
    }
#pragma unroll
    for (int off = 32; off; off >>= 1) {
        l_np += __shfl_down(l_np, off);
        l_l1 += __shfl_down(l_l1, off);
        l_cp += __shfl_down(l_cp, off);
    }
    if (lane == 0) { s_rf[wav * 3] = l_np; s_rf[wav * 3 + 1] = l_l1; s_rf[wav * 3 + 2] = l_cp; }
    __syncthreads();
    if (tid < MM) {
        unsigned int key = s_pk[tid];
        for (int w = 1; w < 4; w++) {
            unsigned int o = s_pk[w * MM + tid];
            if (o > key) key = o;
        }
        int tw  = 255 - (int)(key & 255u);
        int itw = 7 - (int)((key >> 8) & 7u);
        int pm  = p0 + itw * ABLK + tw;
        // global partial: (trunc-iou, 0x7fffffff - p); trunc is chunk-consistent
        partials[((size_t)row * MM + tid) * SPLIT + chunk] =
            ((unsigned long long)(key & 0xFFFFF800u) << 32) |
            (unsigned int)(0x7fffffff - pm);
    }
    if (tid == 0) {
        float np = 0, l1 = 0, cp = 0;
        for (int w = 0; w < 4; w++) { np += s_rf[w * 3]; l1 += s_rf[w * 3 + 1]; cp += s_rf[w * 3 + 2]; }
        float* cs = cstats + ((size_t)row * SPLIT + chunk) * 3;
        cs[0] = np; cs[1] = l1; cs[2] = cp;
    }
}

// ---------------- Kernel B: force prologue + radix-select top-K ----------------
__global__ __launch_bounds__(FBLK) void mbox_sel(
    const float* __restrict__ locs, const float* __restrict__ scores,
    const float* __restrict__ boxes, const int* __restrict__ labels,
    const float* __restrict__ priors,
    const float* __restrict__ cef, const unsigned char* __restrict__ pk8,
    const unsigned long long* __restrict__ partials,
    const float* __restrict__ cstats, float* __restrict__ rstats)
{
    const int row = blockIdx.x, tid = threadIdx.x, lane = tid & 63, wav = tid >> 6;

    __shared__ unsigned int s_u32[PP];              // ce bit patterns
    __shared__ float s_bcx[MM], s_bcy[MM], s_bw[MM], s_bh[MM];
    __shared__ int s_lab[MM], s_pfo[MM];
    __shared__ float s_sum[3];
    __shared__ unsigned int s_hist[256];
    __shared__ unsigned int s_prefix, s_Kr, s_K;
    __shared__ float s_redf[16];
    __shared__ int s_redi[16];

    if (tid < MM) {
        const float* b = boxes + ((size_t)row * MM + tid) * 4;
        float x1 = b[0], y1 = b[1], x2 = b[2], y2 = b[3];
        s_bcx[tid] = (x1 + x2) * 0.5f; s_bcy[tid] = (y1 + y2) * 0.5f;
        s_bw[tid] = x2 - x1; s_bh[tid] = y2 - y1;
        s_lab[tid] = labels[row * MM + tid];
        const unsigned long long* pr = partials + ((size_t)row * MM + tid) * SPLIT;
        unsigned long long key = pr[0];
        for (int c = 1; c < SPLIT; c++) { unsigned long long o = pr[c]; if (o > key) key = o; }
        s_pfo[tid] = 0x7fffffff - (int)(unsigned)(key & 0xffffffffull);
    }
    if (tid >= 16 && tid < 19) {
        int j = tid - 16; float s = 0;
        for (int c = 0; c < SPLIT; c++) s += cstats[((size_t)row * SPLIT + c) * 3 + j];
        s_sum[j] = s;
    }
    // load ce bit patterns into LDS (coalesced)
#pragma unroll
    for (int k = 0; k < EPT; k++) {
        const int p = tid + k * FBLK;
        if (p < PP) s_u32[p] = __float_as_uint(cef[(size_t)row * PP + p]);
    }
    __syncthreads();

    // force deltas (sequential last-wins == group by prior, keep largest m);
    // patches s_u32[p] in place, covered by the next __syncthreads.
    const float4* loc4 = (const float4*)(locs + (size_t)row * PP * 4);
    const float2* sc2  = (const float2*)(scores + (size_t)row * PP * 2);
    float d_np = 0, d_l1 = 0, d_cp = 0;
    if (tid < MM) {
        int p = s_pfo[tid];
        bool is_last = true;
        for (int mm = tid + 1; mm < MM; mm++) if (s_pfo[mm] == p) is_last = false;
        if (is_last) {
            const float4 pr = ((const float4*)priors)[p];
            const float4 pl = loc4[p];
            const float2 sc = sc2[p];
            float lse = lse2(sc.x, sc.y);
            unsigned int u = pk8[(size_t)row * PP + p];
            if (u & 16u) {   // remove old positive contribution
                int mo = u & 15;
                d_np -= 1.0f; d_cp -= (lse - sc.y);
                float tx = (s_bcx[mo] - pr.x) * 10.0f / pr.z;
                float ty = (s_bcy[mo] - pr.y) * 10.0f / pr.w;
                float tw = __logf(s_bw[mo] / pr.z) * 5.0f;
                float th = __logf(s_bh[mo] / pr.w) * 5.0f;
                d_l1 -= fabsf(pl.x - tx) + fabsf(pl.y - ty) + fabsf(pl.z - tw) + fabsf(pl.w - th);
            }
            if (s_lab[tid] != 0) {   // add forced positive (ov=1, m=tid)
                d_np += 1.0f; d_cp += (lse - sc.y);
                float tx = (s_bcx[tid] - pr.x) * 10.0f / pr.z;
                float ty = (s_bcy[tid] - pr.y) * 10.0f / pr.w;
                float tw = __logf(s_bw[tid] / pr.z) * 5.0f;
                float th = __logf(s_bh[tid] / pr.w) * 5.0f;
                d_l1 += fabsf(pl.x - tx) + fabsf(pl.y - ty) + fabsf(pl.z - tw) + fabsf(pl.w - th);
                s_u32[p] = 0u;                             // forced positive -> ce 0
            } else {
                s_u32[p] = __float_as_uint(fmaxf(lse - sc.x, 0.0f)); // forced, label 0
            }
        }
    }
    if (tid < 64) {
#pragma unroll
        for (int off = 32; off; off >>= 1) {
            d_np += __shfl_down(d_np, off);
            d_l1 += __shfl_down(d_l1, off);
            d_cp += __shfl_down(d_cp, off);
        }
        if (tid == 0) {
            float np = s_sum[0] + d_np;
            rstats[(size_t)row * 8 + 0] = np;
            rstats[(size_t)row * 8 + 1] = s_sum[1] + d_l1;
            rstats[(size_t)row * 8 + 2] = s_sum[2] + d_cp;
            int K = NPR * (int)(np + 0.5f);
            s_K = (K > 0) ? (unsigned)K : 0u;
            s_prefix = 0u;
            s_Kr = (K > 0) ? (unsigned)K : 0u;
        }
    }
    __syncthreads();

    // 4-pass 256-bin histogram radix select for the K-th largest bit pattern
    const unsigned int K = s_K;
    unsigned int T = 0u;
    if (K > 0u && K < PP) {
        for (int pass = 0; pass < 4; pass++) {
            const int shift = 24 - 8 * pass;
            if (tid < 256) s_hist[tid] = 0u;
            __syncthreads();
            const unsigned int pref   = s_prefix;
            const unsigned int maskhi = (pass == 0) ? 0u : (0xffffffffu << (shift + 8));
#pragma unroll
            for (int k = 0; k < EPT; k++) {
                const int p = tid + k * FBLK;
                unsigned int u = (p < PP) ? s_u32[p] : 0u;
                if ((u & maskhi) == pref) atomicAdd(&s_hist[(u >> shift) & 255u], 1u);
            }
            __syncthreads();
            if (wav == 0) {
                unsigned int Kr = s_Kr;
                unsigned int h0 = s_hist[lane * 4 + 0];
                unsigned int h1 = s_hist[lane * 4 + 1];
                unsigned int h2 = s_hist[lane * 4 + 2];
                unsigned int h3 = s_hist[lane * 4 + 3];
                unsigned int c3 = h3;
                unsigned int c2 = h3 + h2;
                unsigned int c1 = c2 + h1;
                unsigned int c0 = c1 + h0;
                unsigned int suf = c0;
#pragma unroll
                for (int off = 1; off < 64; off <<= 1) {
                    unsigned int o = __shfl_down(suf, off);
                    if (lane + off < 64) suf += o;
                }
                unsigned int above = suf - c0;
                int cand = -1;
                unsigned int G = 0;
                if      (c3 + above >= Kr) { cand = lane * 4 + 3; G = above + c3 - h3; }
                else if (c2 + above >= Kr) { cand = lane * 4 + 2; G = above + c2 - h2; }
                else if (c1 + above >= Kr) { cand = lane * 4 + 1; G = above + c1 - h1; }
                else if (c0 + above >= Kr) { cand = lane * 4 + 0; G = above + c0 - h0; }
                int best = cand;
#pragma unroll
                for (int off = 32; off; off >>= 1) best = max(best, __shfl_down(best, off));
                best = __shfl(best, 0);
                if (cand == best && cand >= 0) {
                    s_Kr = Kr - G;
                    s_prefix = pref | ((unsigned int)best << shift);
                }
            }
            __syncthreads();
        }
        T = s_prefix;
    }

    // sum strictly greater than pivot + ties * pivot
    float sgt = 0.0f; int cgt = 0;
    if (K > 0u) {
#pragma unroll
        for (int k = 0; k < EPT; k++) {
            const int p = tid + k * FBLK;
            unsigned int u = (p < PP) ? s_u32[p] : 0u;
            if (u > T) { sgt += __uint_as_float(u); cgt++; }
        }
    }
#pragma unroll
    for (int off = 32; off; off >>= 1) {
        sgt += __shfl_down(sgt, off);
        cgt += __shfl_down(cgt, off);
    }
    if (lane == 0) { s_redf[wav] = sgt; s_redi[wav] = cgt; }
    __syncthreads();
    if (tid == 0) {
        float s = 0; int cnt = 0;
        for (int w = 0; w < 16; w++) { s += s_redf[w]; cnt += s_redi[w]; }
        float chard = (K > 0u) ? (s + (float)(int)(K - (unsigned)cnt) * __uint_as_float(T)) : 0.0f;
        rstats[(size_t)row * 8 + 4] = chard;
    }
}

// ---------------- Final cross-row reduction ----------------
__global__ void mbox_finalize(const float* __restrict__ rstats, float* __restrict__ out) {
    int c = threadIdx.x;
    float loss = 0.0f;
    if (c < CC) {
        float np = 0, l1 = 0, cp = 0, ch = 0;
        for (int n = 0; n < NN; n++) {
            const float* s = rstats + ((size_t)(n * CC + c)) * 8;
            np += s[0]; l1 += s[1]; cp += s[2]; ch += s[4];
        }
        float loc = l1 / fmaxf(np * 4.0f, 1.0f);
        float val = (np > 0.0f) ? (cp + ch + loc) / fmaxf(np, 1.0f) : 0.0f;
        loss = val / (float)CC;
    }
#pragma unroll
    for (int off = 32; off; off >>= 1) loss += __shfl_down(loss, off);
    if (threadIdx.x == 0) out[0] = loss;
}

extern "C" void kernel_launch(void* const* d_in, const int* in_sizes, int n_in,
                              void* d_out, int out_size, void* d_ws, size_t ws_size,
                              hipStream_t stream) {
    const float* locs   = (const float*)d_in[0];
    const float* scores = (const float*)d_in[1];
    const float* boxes  = (const float*)d_in[2];
    const int*   labels = (const int*)d_in[3];
    const float* priors = (const float*)d_in[4];
    float* out = (float*)d_out;

    char* ws = (char*)d_ws;
    float* cef                   = (float*)ws;                          // 5,588,480 B
    unsigned char* pk8           = (unsigned char*)(ws + 5588480);      // 1,397,120 B
    unsigned long long* partials = (unsigned long long*)(ws + 6985600); //   245,760 B
    float* cstats                = (float*)(ws + 7231360);              //    23,040 B
    float* rstats                = (float*)(ws + 7254400);              //     5,120 B

    mbox_p1<<<ROWS * SPLIT, ABLK, 0, stream>>>(locs, scores, boxes, labels, priors,
                                               cef, pk8, partials, cstats);
    mbox_sel<<<ROWS, FBLK, 0, stream>>>(locs, scores, boxes, labels, priors,
                                        cef, pk8, partials, cstats, rstats);
    mbox_finalize<<<1, 64, 0, stream>>>(rstats, out);
}